// Round 2
// baseline (235.006 us; speedup 1.0000x reference)
//
#include <hip/hip_runtime.h>
#include <hip/hip_bf16.h>

// ContrastiveLoss: B=4096 rows, D=128 feature dim, C=100 classes.
// loss = -(1/B^2) * sum_c count_c * G_c / (count_c + 1e-12)
//   G_c  = sum_{k: label_k=c} S_k
//   S_k  = sum_j logits[k,j] - B*m_k - B*log(Z_k + 1e-12)
//   logits[k,j] = w_k . a_j,  w_k = (a_k + (a_k @ Cov[l_k]) / (2 T^2)) / T

#define DIM 128
#define TEMP 0.07f

__global__ void count_kernel(const int* __restrict__ labels,
                             int* __restrict__ counts, int B) {
    int i = blockIdx.x * 256 + threadIdx.x;
    if (i < B) atomicAdd(&counts[labels[i]], 1);
}

// One block per row i: w_i[e] = (a_i[e] + (sum_d a_i[d]*Cov[c][d][e]) * inv2t2) * invt
__global__ __launch_bounds__(128) void w_kernel(
    const float* __restrict__ A, const int* __restrict__ labels,
    const float* __restrict__ Cov, float* __restrict__ W) {
    const float inv2t2 = 1.0f / (2.0f * TEMP * TEMP);
    const float invt = 1.0f / TEMP;
    int i = blockIdx.x;
    int e = threadIdx.x;
    __shared__ float a[DIM];
    a[e] = A[(size_t)i * DIM + e];
    __syncthreads();
    int c = labels[i];
    const float* Cp = Cov + (size_t)c * (DIM * DIM) + e;
    float acc = 0.0f;
#pragma unroll 8
    for (int d = 0; d < DIM; ++d) {
        acc = fmaf(a[d], Cp[(size_t)d * DIM], acc);
    }
    W[(size_t)i * DIM + e] = (a[e] + acc * inv2t2) * invt;
}

// Lane = one row k; w_k lives in 128 VGPRs (launch_bounds(64,1) -> no spill).
// Wave iterates a 64-column j-chunk; a_j loads are wave-uniform (SGPR
// broadcast). Per-lane online softmax state (m, Z, sumLogits).
// grid = (B/64 j-chunks) x (B/64 k-blocks), block = 64 threads (1 wave).
__global__ __launch_bounds__(64, 1) void main_kernel(
    const float* __restrict__ A, const float* __restrict__ W,
    float* __restrict__ mP, float* __restrict__ zP, float* __restrict__ sP,
    int B) {
    int nJB = B >> 6;
    int jb = blockIdx.x % nJB;
    int kb = blockIdx.x / nJB;
    int lane = threadIdx.x;
    int k = kb * 64 + lane;

    // Load w_k into registers (per-lane distinct -> vector loads).
    float4 w[DIM / 4];
    const float4* wp = (const float4*)(W + (size_t)k * DIM);
#pragma unroll
    for (int d = 0; d < DIM / 4; ++d) w[d] = wp[d];

    float m = -3.4e38f, Z = 0.0f, sL = 0.0f;
    const float4* ap = (const float4*)(A + (size_t)jb * 64 * DIM);

#pragma unroll 2
    for (int jj = 0; jj < 64; ++jj) {
        const float4* aj = ap + jj * (DIM / 4);
        float dot = 0.0f;
#pragma unroll
        for (int d = 0; d < DIM / 4; ++d) {
            float4 av = aj[d];  // wave-uniform address -> scalar-load broadcast
            dot = fmaf(w[d].x, av.x, dot);
            dot = fmaf(w[d].y, av.y, dot);
            dot = fmaf(w[d].z, av.z, dot);
            dot = fmaf(w[d].w, av.w, dot);
        }
        sL += dot;
        float mn = fmaxf(m, dot);
        Z = Z * __expf(m - mn) + __expf(dot - mn);
        m = mn;
    }
    size_t idx = (size_t)k * nJB + jb;
    mP[idx] = m;
    zP[idx] = Z;
    sP[idx] = sL;
}

// One wave per row k: merge the nJB partial (m,Z,s) triples, compute S_k,
// accumulate into per-class G (double atomics).
__global__ __launch_bounds__(64) void combine_kernel(
    const float* __restrict__ mP, const float* __restrict__ zP,
    const float* __restrict__ sP, const int* __restrict__ labels,
    double* __restrict__ G, int B) {
    int k = blockIdx.x;
    int l = threadIdx.x;
    int nJB = B >> 6;
    float m = -3.4e38f, Z = 0.0f, s = 0.0f;
    if (l < nJB) {
        size_t idx = (size_t)k * nJB + l;
        m = mP[idx];
        Z = zP[idx];
        s = sP[idx];
    }
    float M = m;
#pragma unroll
    for (int o = 32; o > 0; o >>= 1) M = fmaxf(M, __shfl_xor(M, o));
    float zt = Z * __expf(m - M);
    float st = s;
#pragma unroll
    for (int o = 32; o > 0; o >>= 1) {
        zt += __shfl_xor(zt, o);
        st += __shfl_xor(st, o);
    }
    if (l == 0) {
        double Sk = (double)st - (double)B * (double)M
                    - (double)B * log((double)zt + 1e-12);
        atomicAdd(&G[labels[k]], Sk);
    }
}

__global__ __launch_bounds__(128) void final_kernel(
    const double* __restrict__ G, const int* __restrict__ counts,
    float* __restrict__ out, int C, double invB2) {
    __shared__ double sh[128];
    int t = threadIdx.x;
    double v = 0.0;
    if (t < C) {
        double cnt = (double)counts[t];
        v = G[t] * (cnt / (cnt + 1e-12));
    }
    sh[t] = v;
    __syncthreads();
    for (int o = 64; o > 0; o >>= 1) {
        if (t < o) sh[t] += sh[t + o];
        __syncthreads();
    }
    if (t == 0) out[0] = (float)(-sh[0] * invB2);
}

extern "C" void kernel_launch(void* const* d_in, const int* in_sizes, int n_in,
                              void* d_out, int out_size, void* d_ws, size_t ws_size,
                              hipStream_t stream) {
    const float* A = (const float*)d_in[0];
    const int* labels = (const int*)d_in[1];
    const float* Cov = (const float*)d_in[2];
    float* out = (float*)d_out;

    int B = in_sizes[0] / DIM;            // 4096
    int C = in_sizes[2] / (DIM * DIM);    // 100
    int nJB = B >> 6;                     // 64

    char* ws = (char*)d_ws;
    float* W = (float*)ws;                                    // B*128 f32 (2 MB)
    float* mP = (float*)(ws + (size_t)B * DIM * 4);           // B*nJB f32 (1 MB)
    float* zP = mP + (size_t)B * nJB;
    float* sP = zP + (size_t)B * nJB;
    double* G = (double*)(sP + (size_t)B * nJB);              // C doubles
    int* counts = (int*)(G + C);                              // C ints

    // zero G + counts (contiguous)
    hipMemsetAsync(G, 0, (size_t)C * (sizeof(double) + sizeof(int)), stream);

    count_kernel<<<(B + 255) / 256, 256, 0, stream>>>(labels, counts, B);
    w_kernel<<<B, 128, 0, stream>>>(A, labels, Cov, W);
    main_kernel<<<nJB * (B / 64), 64, 0, stream>>>(A, W, mP, zP, sP, B);
    combine_kernel<<<B, 64, 0, stream>>>(mP, zP, sP, labels, G, B);
    final_kernel<<<1, 128, 0, stream>>>(G, counts, out, C,
                                        1.0 / ((double)B * (double)B));
}

// Round 3
// 114.235 us; speedup vs baseline: 2.0572x; 2.0572x over previous
//
#include <hip/hip_runtime.h>
#include <hip/hip_bf16.h>

// ContrastiveLoss: B=4096 rows, D=128 feature dim, C=100 classes.
// loss = -(1/B^2) * sum_c count_c * G_c / (count_c + 1e-12)
//   G_c  = sum_{k: label_k=c} S_k
//   S_k  = sum_j logits[k,j] - B*m_k - B*log(Z_k + 1e-12)
//   logits[k,j] = w_k . a_j,  w_k = (a_k + (a_k @ Cov[l_k]) / (2 T^2)) / T
// Main pass: bf16 MFMA (16x16x32) flash-style, online softmax per row.

#define DIM 128
#define TEMP 0.07f
#define PITCH 136  // LDS row pitch in bf16 elems (128 + 8 pad -> 2-way-max bank conflicts)

typedef __attribute__((ext_vector_type(8))) short short8;
typedef __attribute__((ext_vector_type(4))) float floatx4;

static __device__ __forceinline__ unsigned short f2bf(float f) {
    __hip_bfloat16 h = __float2bfloat16(f);
    union { __hip_bfloat16 h; unsigned short u; } c;
    c.h = h;
    return c.u;
}

// fp32 -> bf16 conversion of A (B*DIM elements)
__global__ __launch_bounds__(256) void conv_kernel(
    const float* __restrict__ A, unsigned short* __restrict__ O, int n) {
    int i = (blockIdx.x * 256 + threadIdx.x) * 4;
    if (i < n) {
        float4 v = *(const float4*)(A + i);
        ushort4 o;
        o.x = f2bf(v.x); o.y = f2bf(v.y); o.z = f2bf(v.z); o.w = f2bf(v.w);
        *(ushort4*)(O + i) = o;
    }
}

// One block per row i: w_i[e] = (a_i[e] + (sum_d a_i[d]*Cov[c][d][e]) * inv2t2) * invt
// Uses fp32 A (full precision for the bilinear part), outputs bf16 W.
__global__ __launch_bounds__(128) void w_kernel(
    const float* __restrict__ A, const int* __restrict__ labels,
    const float* __restrict__ Cov, unsigned short* __restrict__ Wbf) {
    const float inv2t2 = 1.0f / (2.0f * TEMP * TEMP);
    const float invt = 1.0f / TEMP;
    int i = blockIdx.x;
    int e = threadIdx.x;
    __shared__ float a[DIM];
    a[e] = A[(size_t)i * DIM + e];
    __syncthreads();
    int c = labels[i];
    const float* Cp = Cov + (size_t)c * (DIM * DIM) + e;
    float acc = 0.0f;
#pragma unroll 8
    for (int d = 0; d < DIM; ++d) {
        acc = fmaf(a[d], Cp[(size_t)d * DIM], acc);
    }
    Wbf[(size_t)i * DIM + e] = f2bf((a[e] + acc * inv2t2) * invt);
}

// Block = 4 waves (2M x 2N). Block tile: 128 k-rows x 64 j-cols, K=128 unrolled.
// Wave tile: 64x32 via 4(m) x 2(n) mfma_f32_16x16x32_bf16 accumulators.
// Each lane keeps online-softmax state for its 16 rows over ITS column subset
// (no cross-lane ops in the j-loop); one 16-lane merge at the end.
// grid = (B/128 m-blocks) * Jsplit; each block sweeps JSWEEP j-tiles of 64.
__global__ __launch_bounds__(256, 2) void main_kernel(
    const unsigned short* __restrict__ Wbf, const unsigned short* __restrict__ Abf,
    float* __restrict__ mP, float* __restrict__ zP, float* __restrict__ sP,
    int Jsplit, int JSWEEP, int nP) {
    __shared__ __align__(16) unsigned short sW[128 * PITCH];
    __shared__ __align__(16) unsigned short sA[64 * PITCH];

    const int mb = blockIdx.x / Jsplit;
    const int jsp = blockIdx.x % Jsplit;
    const int rowBase = mb * 128;
    const int t = threadIdx.x;
    const int wave = t >> 6, lane = t & 63, quad = lane >> 4, l16 = lane & 15;
    const int waveM = wave >> 1, waveN = wave & 1;

    // stage W tile (128 rows x 128 bf16), once
    {
        int row = t >> 1, half = t & 1;
        const unsigned short* src = Wbf + (size_t)(rowBase + row) * DIM + half * 64;
        unsigned short* dst = sW + row * PITCH + half * 64;
#pragma unroll
        for (int i = 0; i < 8; i++)
            *(short8*)(dst + i * 8) = *(const short8*)(src + i * 8);
    }

    float run_m[4][4], run_Z[4][4], run_s[4][4];
#pragma unroll
    for (int a = 0; a < 4; a++)
#pragma unroll
        for (int r = 0; r < 4; r++) {
            run_m[a][r] = -3.4e38f; run_Z[a][r] = 0.f; run_s[a][r] = 0.f;
        }

    const unsigned short* myW = sW + (waveM * 64 + l16) * PITCH;
    const unsigned short* myA = sA + (waveN * 32 + l16) * PITCH;

    for (int js = 0; js < JSWEEP; ++js) {
        __syncthreads();  // protect sA overwrite (and sW on first iter)
        {   // stage A tile (64 rows x 128 bf16)
            int row = t >> 2, q = t & 3;
            int j0 = (jsp * JSWEEP + js) * 64;
            const unsigned short* src = Abf + (size_t)(j0 + row) * DIM + q * 32;
            unsigned short* dst = sA + row * PITCH + q * 32;
#pragma unroll
            for (int i = 0; i < 4; i++)
                *(short8*)(dst + i * 8) = *(const short8*)(src + i * 8);
        }
        __syncthreads();

        floatx4 acc[4][2];
#pragma unroll
        for (int mt = 0; mt < 4; mt++)
#pragma unroll
            for (int nt = 0; nt < 2; nt++) acc[mt][nt] = (floatx4)0.f;

#pragma unroll
        for (int kst = 0; kst < 4; ++kst) {
            const int koff = kst * 32 + quad * 8;
            short8 bfrag[2];
#pragma unroll
            for (int nt = 0; nt < 2; nt++)
                bfrag[nt] = *(const short8*)(myA + nt * 16 * PITCH + koff);
#pragma unroll
            for (int mt = 0; mt < 4; mt++) {
                short8 afrag = *(const short8*)(myW + mt * 16 * PITCH + koff);
#pragma unroll
                for (int nt = 0; nt < 2; nt++)
                    acc[mt][nt] = __builtin_amdgcn_mfma_f32_16x16x32_bf16(
                        afrag, bfrag[nt], acc[mt][nt], 0, 0, 0);
            }
        }

        // per-lane online softmax update (lane's 2 columns only; no shfl)
#pragma unroll
        for (int mt = 0; mt < 4; mt++)
#pragma unroll
            for (int r = 0; r < 4; r++) {
                float v0 = acc[mt][0][r], v1 = acc[mt][1][r];
                float tm = fmaxf(v0, v1);
                float nm = fmaxf(run_m[mt][r], tm);
                run_Z[mt][r] = run_Z[mt][r] * __expf(run_m[mt][r] - nm)
                             + __expf(v0 - nm) + __expf(v1 - nm);
                run_m[mt][r] = nm;
                run_s[mt][r] += v0 + v1;
            }
    }

    // merge across the 16 lanes sharing each row, then write partials
    const int chunk = jsp * 2 + waveN;
#pragma unroll
    for (int mt = 0; mt < 4; mt++)
#pragma unroll
        for (int r = 0; r < 4; r++) {
            float m = run_m[mt][r], Z = run_Z[mt][r], s = run_s[mt][r];
#pragma unroll
            for (int mask = 1; mask < 16; mask <<= 1) {
                float om = __shfl_xor(m, mask);
                float oZ = __shfl_xor(Z, mask);
                float os = __shfl_xor(s, mask);
                float nm = fmaxf(m, om);
                Z = Z * __expf(m - nm) + oZ * __expf(om - nm);
                m = nm;
                s += os;
            }
            if (l16 == r) {
                int row = rowBase + waveM * 64 + mt * 16 + quad * 4 + r;
                size_t idx = (size_t)row * nP + chunk;
                mP[idx] = m; zP[idx] = Z; sP[idx] = s;
            }
        }
}

// One wave per row k: merge nP partial (m,Z,s) triples, compute S_k,
// accumulate per-class G (double atomics) and class counts.
__global__ __launch_bounds__(64) void combine_kernel(
    const float* __restrict__ mP, const float* __restrict__ zP,
    const float* __restrict__ sP, const int* __restrict__ labels,
    double* __restrict__ G, int* __restrict__ counts, int B, int nP) {
    int k = blockIdx.x;
    int l = threadIdx.x;
    float m = -3.4e38f, Z = 0.0f, s = 0.0f;
    if (l < nP) {
        size_t idx = (size_t)k * nP + l;
        m = mP[idx]; Z = zP[idx]; s = sP[idx];
    }
    float M = m;
#pragma unroll
    for (int o = 32; o > 0; o >>= 1) M = fmaxf(M, __shfl_xor(M, o));
    float zt = Z * __expf(m - M);
    float st = s;
#pragma unroll
    for (int o = 32; o > 0; o >>= 1) {
        zt += __shfl_xor(zt, o);
        st += __shfl_xor(st, o);
    }
    if (l == 0) {
        double Sk = (double)st - (double)B * (double)M
                    - (double)B * log((double)zt + 1e-12);
        int c = labels[k];
        atomicAdd(&G[c], Sk);
        atomicAdd(&counts[c], 1);
    }
}

__global__ __launch_bounds__(128) void final_kernel(
    const double* __restrict__ G, const int* __restrict__ counts,
    float* __restrict__ out, int C, double invB2) {
    __shared__ double sh[128];
    int t = threadIdx.x;
    double v = 0.0;
    if (t < C) {
        double cnt = (double)counts[t];
        v = G[t] * (cnt / (cnt + 1e-12));
    }
    sh[t] = v;
    __syncthreads();
    for (int o = 64; o > 0; o >>= 1) {
        if (t < o) sh[t] += sh[t + o];
        __syncthreads();
    }
    if (t == 0) out[0] = (float)(-sh[0] * invB2);
}

extern "C" void kernel_launch(void* const* d_in, const int* in_sizes, int n_in,
                              void* d_out, int out_size, void* d_ws, size_t ws_size,
                              hipStream_t stream) {
    const float* A = (const float*)d_in[0];
    const int* labels = (const int*)d_in[1];
    const float* Cov = (const float*)d_in[2];
    float* out = (float*)d_out;

    int B = in_sizes[0] / DIM;            // 4096
    int C = in_sizes[2] / (DIM * DIM);    // 100
    int Jsplit = 16;
    int JSWEEP = B / (Jsplit * 64);       // 4
    int nP = Jsplit * 2;                  // 32 partials per row

    char* ws = (char*)d_ws;
    unsigned short* Wbf = (unsigned short*)ws;                       // B*128 bf16 (1 MB)
    unsigned short* Abf = Wbf + (size_t)B * DIM;                     // B*128 bf16 (1 MB)
    float* mP = (float*)(Abf + (size_t)B * DIM);                     // B*nP f32
    float* zP = mP + (size_t)B * nP;
    float* sP = zP + (size_t)B * nP;
    double* G = (double*)(sP + (size_t)B * nP);                      // C doubles
    int* counts = (int*)(G + C);                                     // C ints

    // zero G + counts (contiguous)
    hipMemsetAsync(G, 0, (size_t)C * (sizeof(double) + sizeof(int)), stream);

    int nA = B * DIM;
    conv_kernel<<<(nA / 4 + 255) / 256, 256, 0, stream>>>(A, Abf, nA);
    w_kernel<<<B, 128, 0, stream>>>(A, labels, Cov, Wbf);
    main_kernel<<<(B / 128) * Jsplit, 256, 0, stream>>>(Wbf, Abf, mP, zP, sP,
                                                        Jsplit, JSWEEP, nP);
    combine_kernel<<<B, 64, 0, stream>>>(mP, zP, sP, labels, G, counts, B, nP);
    final_kernel<<<1, 128, 0, stream>>>(G, counts, out, C,
                                        1.0 / ((double)B * (double)B));
}